// Round 10
// baseline (146.622 us; speedup 1.0000x reference)
//
#include <hip/hip_runtime.h>
#include <math.h>

namespace {

constexpr int Bn = 8, Cn = 256, CIN = 128, Wd = 128, Hd = 128, ATTn = 32, Nn = ATTn * ATTn;

typedef __attribute__((ext_vector_type(8))) short short8;
typedef __attribute__((ext_vector_type(4))) float f32x4;

__device__ inline unsigned short bf16_rne(float f) {
    unsigned int u = __float_as_uint(f);
    unsigned int r = (u + 0x7FFFu + ((u >> 16) & 1u)) >> 16;
    return (unsigned short)r;
}

__device__ inline int fsw(int px) { return (px ^ (px >> 3)) & 7; }

// ---------------- Kernel 1a: pool1 v8 — 8 loads/thread in flight, oy-pair per block --------
// 4096 blocks = b(8) x oyp(16) x cg(32). Thread (c8 = t>>5, ox = t&31): 8 independent
// float4 loads (rows oyp*8 .. +7 of channel cg*8+c8), two windows reduced in-register,
// one barrier + LDS transpose, coalesced float2 stores.
__global__ __launch_bounds__(256) void pool1_kernel(const float* __restrict__ in1,
                                                    float* __restrict__ p1t) {
    __shared__ float tile[2][32][9];
    const int t = threadIdx.x;
    const int bid = blockIdx.x;
    const int cg = bid & 31, oyp = (bid >> 5) & 15, b = bid >> 9;
    const int c8 = t >> 5, ox = t & 31;

    const float* src = in1 + (((size_t)(b * Cn + cg * 8 + c8) * Wd) + oyp * 8) * Hd + ox * 4;
    f32x4 r[8];
#pragma unroll
    for (int j = 0; j < 8; ++j)
        r[j] = *reinterpret_cast<const f32x4*>(src + (size_t)j * Hd);

    float mx0 = -INFINITY, sm0 = 0.f, mx1 = -INFINITY, sm1 = 0.f;
#pragma unroll
    for (int j = 0; j < 4; ++j) {
        mx0 = fmaxf(mx0, fmaxf(fmaxf(r[j][0], r[j][1]), fmaxf(r[j][2], r[j][3])));
        sm0 += (r[j][0] + r[j][1]) + (r[j][2] + r[j][3]);
    }
#pragma unroll
    for (int j = 4; j < 8; ++j) {
        mx1 = fmaxf(mx1, fmaxf(fmaxf(r[j][0], r[j][1]), fmaxf(r[j][2], r[j][3])));
        sm1 += (r[j][0] + r[j][1]) + (r[j][2] + r[j][3]);
    }
    tile[0][ox][c8] = mx0 + sm0 * (1.f / 16.f);
    tile[1][ox][c8] = mx1 + sm1 * (1.f / 16.f);
    __syncthreads();

    const int wnd = t >> 7, rr = t & 127, ox2 = rr >> 2, cp = rr & 3;
    const float a0 = tile[wnd][ox2][cp * 2];
    const float a1 = tile[wnd][ox2][cp * 2 + 1];
    *reinterpret_cast<float2*>(p1t + ((size_t)b * Nn + (oyp * 2 + wnd) * 32 + ox2) * Cn
                               + cg * 8 + cp * 2) = make_float2(a0, a1);
}

// ---------------- Kernel 1b: convpool — r7 core, occupancy 4 blocks/CU ---------------------
__global__ __launch_bounds__(512, 8) void convpool_kernel(const float* __restrict__ in2,
                                                          const float* __restrict__ cw,
                                                          const float* __restrict__ cb,
                                                          float* __restrict__ p2t) {
    __shared__ __align__(16) unsigned char smem[32768];

    const int t = threadIdx.x;
    const int w = t >> 6;                 // wave 0..7
    const int l = t & 63;
    const int bid2 = blockIdx.x;          // 0..1023
    const int b = bid2 >> 7;
    const int r = bid2 & 127;
    const int oy = r >> 2, xq = r & 3;

    // ---- stage: 2 tasks/thread, 4 channel-strided float4 each
    f32x4 ra[2][4];
    int x4v[2], rowv[2], k4v[2];
#pragma unroll
    for (int h = 0; h < 2; ++h) {
        const int i = t + h * 512;
        x4v[h] = i & 7; rowv[h] = (i >> 3) & 3; k4v[h] = i >> 5;
        const float* p = in2 + ((size_t)(b * CIN + k4v[h] * 4) * Wd + oy * 4 + rowv[h]) * Hd
                         + xq * 32 + x4v[h] * 4;
#pragma unroll
        for (int kk2 = 0; kk2 < 4; ++kk2)
            ra[h][kk2] = *reinterpret_cast<const f32x4*>(p + (size_t)kk2 * Wd * Hd);
    }

    // ---- B fragments (weights) in registers
    const int n_lo = l & 15;
    const int khi = l >> 4;
    short8 bfrag[2][4];
#pragma unroll
    for (int f = 0; f < 2; ++f) {
        const int n = w * 32 + f * 16 + n_lo;
#pragma unroll
        for (int kk = 0; kk < 4; ++kk) {
            const float* wp = cw + n * CIN + kk * 32 + khi * 8;
            f32x4 va = *reinterpret_cast<const f32x4*>(wp);
            f32x4 vb = *reinterpret_cast<const f32x4*>(wp + 4);
            short8 s;
            s[0] = (short)bf16_rne(va[0]); s[1] = (short)bf16_rne(va[1]);
            s[2] = (short)bf16_rne(va[2]); s[3] = (short)bf16_rne(va[3]);
            s[4] = (short)bf16_rne(vb[0]); s[5] = (short)bf16_rne(vb[1]);
            s[6] = (short)bf16_rne(vb[2]); s[7] = (short)bf16_rne(vb[3]);
            bfrag[f][kk] = s;
        }
    }
    const float bias2_0 = 2.f * cb[w * 32 + n_lo];
    const float bias2_1 = 2.f * cb[w * 32 + 16 + n_lo];

    // ---- transpose + swizzled LDS write: A[px][k] bf16
#pragma unroll
    for (int h = 0; h < 2; ++h) {
#pragma unroll
        for (int j = 0; j < 4; ++j) {
            const int px = x4v[h] * 16 + rowv[h] * 4 + j;
            uint2 u;
            u.x = (unsigned int)bf16_rne(ra[h][0][j]) | ((unsigned int)bf16_rne(ra[h][1][j]) << 16);
            u.y = (unsigned int)bf16_rne(ra[h][2][j]) | ((unsigned int)bf16_rne(ra[h][3][j]) << 16);
            const int off = px * 256 + ((k4v[h] * 8) ^ (fsw(px) << 4));
            *reinterpret_cast<uint2*>(smem + off) = u;
        }
    }
    __syncthreads();

    // ---- per-wave: 8 cells x 2 n-tiles; K=128 inner, pool epilogue per cell
#pragma unroll
    for (int cl = 0; cl < 8; ++cl) {
        f32x4 acc0 = {0.f, 0.f, 0.f, 0.f};
        f32x4 acc1 = {0.f, 0.f, 0.f, 0.f};
        const int px = cl * 16 + n_lo;
        const int sw = fsw(px) << 4;
#pragma unroll
        for (int kk = 0; kk < 4; ++kk) {
            short8 a = *reinterpret_cast<const short8*>(
                smem + px * 256 + ((kk * 64 + khi * 16) ^ sw));
            acc0 = __builtin_amdgcn_mfma_f32_16x16x32_bf16(a, bfrag[0][kk], acc0, 0, 0, 0);
            acc1 = __builtin_amdgcn_mfma_f32_16x16x32_bf16(a, bfrag[1][kk], acc1, 0, 0, 0);
        }
        float mx0 = fmaxf(fmaxf(acc0[0], acc0[1]), fmaxf(acc0[2], acc0[3]));
        float sm0 = (acc0[0] + acc0[1]) + (acc0[2] + acc0[3]);
        float mx1 = fmaxf(fmaxf(acc1[0], acc1[1]), fmaxf(acc1[2], acc1[3]));
        float sm1 = (acc1[0] + acc1[1]) + (acc1[2] + acc1[3]);
        mx0 = fmaxf(mx0, __shfl_xor(mx0, 16)); sm0 += __shfl_xor(sm0, 16);
        mx0 = fmaxf(mx0, __shfl_xor(mx0, 32)); sm0 += __shfl_xor(sm0, 32);
        mx1 = fmaxf(mx1, __shfl_xor(mx1, 16)); sm1 += __shfl_xor(sm1, 16);
        mx1 = fmaxf(mx1, __shfl_xor(mx1, 32)); sm1 += __shfl_xor(sm1, 32);
        if (l < 16) {
            const int cell = oy * 32 + xq * 8 + cl;
            float* dst = p2t + ((size_t)b * Nn + cell) * Cn + w * 32 + n_lo;
            dst[0]  = mx0 + sm0 * (1.f / 16.f) + bias2_0;
            dst[16] = mx1 + sm1 * (1.f / 16.f) + bias2_1;
        }
    }
}

// ---------------- Kernel 2: per-cell cross-batch attention -> att[b][c][n] ----------------
__global__ __launch_bounds__(256) void attn_kernel(const float* __restrict__ p1t,
                                                   const float* __restrict__ p2t,
                                                   float* __restrict__ att) {
    __shared__ float q[Bn][260];
    __shared__ float kk[Bn][260];
    __shared__ float wsm[Bn][8];
    const int n = blockIdx.x, t = threadIdx.x;

#pragma unroll
    for (int i = 0; i < 2; ++i) {
        const int f = t + i * 256;
        const int bb = f >> 6, cq = f & 63;
        const size_t off = ((size_t)bb * Nn + n) * Cn + cq * 4;
        *reinterpret_cast<float4*>(&q[bb][cq * 4])  = *reinterpret_cast<const float4*>(p1t + off);
        *reinterpret_cast<float4*>(&kk[bb][cq * 4]) = *reinterpret_cast<const float4*>(p2t + off);
    }
    __syncthreads();

    {
        const int chunk = t & 3, pair = t >> 2;
        const int e = pair & 7, bb = pair >> 3;
        float s = 0.f;
#pragma unroll
        for (int i = 0; i < 64; ++i)
            s = fmaf(q[bb][i * 4 + chunk], kk[e][i * 4 + chunk], s);
        s += __shfl_xor(s, 1);
        s += __shfl_xor(s, 2);
        s *= 0.17677669529663687f;            // 1/sqrt(32)
        float m = fmaxf(s, __shfl_xor(s, 4));
        m = fmaxf(m, __shfl_xor(m, 8));
        m = fmaxf(m, __shfl_xor(m, 16));
        float p = __expf(s - m);
        float d = p + __shfl_xor(p, 4);
        d += __shfl_xor(d, 8);
        d += __shfl_xor(d, 16);
        if (chunk == 0) wsm[bb][e] = p / d;
    }
    __syncthreads();

    float kv[8];
#pragma unroll
    for (int e = 0; e < 8; ++e) kv[e] = kk[e][t];
#pragma unroll
    for (int bb = 0; bb < 8; ++bb) {
        float s = 0.f;
#pragma unroll
        for (int e = 0; e < 8; ++e) s = fmaf(wsm[bb][e], kv[e], s);
        att[((size_t)bb * Cn + t) * Nn + n] = s;
    }
}

// ---------------- Kernel 3: bilinear upsample (align_corners) + sigmoid ----------------
__global__ __launch_bounds__(256) void upsample_kernel(const float* __restrict__ att,
                                                       float* __restrict__ out) {
    __shared__ float tile[ATTn * ATTn];
    int bc = blockIdx.x, t = threadIdx.x;
    reinterpret_cast<float4*>(tile)[t] =
        reinterpret_cast<const float4*>(att + (size_t)bc * Nn)[t];
    __syncthreads();

    int tx = t & 31, ty = t >> 5;
    int xi0[4], xi1[4];
    float xt[4];
#pragma unroll
    for (int j = 0; j < 4; ++j) {
        int x = tx * 4 + j;
        float pos = (float)x * (31.f / 127.f);
        int i0 = (int)pos;
        xi0[j] = i0;
        xi1[j] = min(i0 + 1, 31);
        xt[j] = pos - (float)i0;
    }

    for (int r = 0; r < 16; ++r) {
        int y = ty + r * 8;
        float posy = (float)y * (31.f / 127.f);
        int y0 = (int)posy;
        int y1 = min(y0 + 1, 31);
        float ft = posy - (float)y0;
        float o_[4];
#pragma unroll
        for (int j = 0; j < 4; ++j) {
            float v00 = tile[y0 * 32 + xi0[j]];
            float v01 = tile[y0 * 32 + xi1[j]];
            float v10 = tile[y1 * 32 + xi0[j]];
            float v11 = tile[y1 * 32 + xi1[j]];
            float top = v00 * (1.f - ft) + v10 * ft;
            float bot = v01 * (1.f - ft) + v11 * ft;
            float val = top * (1.f - xt[j]) + bot * xt[j];
            o_[j] = 1.f / (1.f + __expf(-val));
        }
        *reinterpret_cast<float4*>(out + ((size_t)bc * Wd + y) * Hd + tx * 4) =
            make_float4(o_[0], o_[1], o_[2], o_[3]);
    }
}

}  // namespace

extern "C" void kernel_launch(void* const* d_in, const int* in_sizes, int n_in,
                              void* d_out, int out_size, void* d_ws, size_t ws_size,
                              hipStream_t stream) {
    const float* input1 = (const float*)d_in[0];
    const float* input2 = (const float*)d_in[1];
    const float* conv_w = (const float*)d_in[2];
    const float* conv_b = (const float*)d_in[3];
    float* out = (float*)d_out;

    float* p1t = (float*)d_ws;                        // [B][N][C] 8 MB
    float* p2t = p1t + (size_t)Bn * Cn * Nn;          // [B][N][C] 8 MB
    float* att = p2t + (size_t)Bn * Cn * Nn;          // [B][C][N] 8 MB

    pool1_kernel<<<dim3(4096), dim3(256), 0, stream>>>(input1, p1t);
    convpool_kernel<<<dim3(1024), dim3(512), 0, stream>>>(input2, conv_w, conv_b, p2t);
    attn_kernel<<<dim3(Nn), dim3(256), 0, stream>>>(p1t, p2t, att);
    upsample_kernel<<<dim3(Bn * Cn), dim3(256), 0, stream>>>(att, out);
}

// Round 11
// 104.778 us; speedup vs baseline: 1.3994x; 1.3994x over previous
//
#include <hip/hip_runtime.h>
#include <math.h>

namespace {

constexpr int Bn = 8, Cn = 256, CIN = 128, Wd = 128, Hd = 128, ATTn = 32, Nn = ATTn * ATTn;

typedef __attribute__((ext_vector_type(8))) short short8;
typedef __attribute__((ext_vector_type(4))) float f32x4;

__device__ inline unsigned short bf16_rne(float f) {
    unsigned int u = __float_as_uint(f);
    unsigned int r = (u + 0x7FFFu + ((u >> 16) & 1u)) >> 16;
    return (unsigned short)r;
}

__device__ inline int fsw(int px) { return (px ^ (px >> 3)) & 7; }

__device__ inline f32x4 ldnt(const float* p) {
    return __builtin_nontemporal_load(reinterpret_cast<const f32x4*>(p));
}

// ============ Fused front kernel (r4 structure, nt loads) ============
// blocks [0,256):    pool1  — block (b,oy); wave-private, coalesced, no barriers.
// blocks [256,1280): convpool — block (b,oy,xq); one-shot stage + 1 barrier + MFMA.
__global__ __launch_bounds__(512, 4) void front_kernel(const float* __restrict__ in1,
                                                       const float* __restrict__ in2,
                                                       const float* __restrict__ cw,
                                                       const float* __restrict__ cb,
                                                       float* __restrict__ p1t,
                                                       float* __restrict__ p2t) {
    __shared__ __align__(16) unsigned char smem[33792];

    const int t = threadIdx.x;
    const int bid = blockIdx.x;
    const int w = t >> 6;                 // wave 0..7
    const int l = t & 63;                 // lane

    if (bid < 256) {
        // ---------------- pool1: adaptive max+avg pool of in1 -> p1t[b][n][c] -------------
        const int b = bid >> 5, oy = bid & 31;
        float* tile = reinterpret_cast<float*>(smem) + w * 1056;   // [32 ox][33] f32
        const int x4 = l & 31, dyp = l >> 5;
        const float* base = in1 + ((size_t)(b * Cn + w * 32) * Wd + oy * 4 + dyp) * Hd + x4 * 4;
#pragma unroll 4
        for (int ch = 0; ch < 32; ++ch) {
            const float* p = base + (size_t)ch * Wd * Hd;
            f32x4 v0 = ldnt(p);
            f32x4 v1 = ldnt(p + 2 * Hd);
            float mx = fmaxf(fmaxf(fmaxf(v0[0], v0[1]), fmaxf(v0[2], v0[3])),
                             fmaxf(fmaxf(v1[0], v1[1]), fmaxf(v1[2], v1[3])));
            float sm = ((v0[0] + v0[1]) + (v0[2] + v0[3])) +
                       ((v1[0] + v1[1]) + (v1[2] + v1[3]));
            mx = fmaxf(mx, __shfl_xor(mx, 32));
            sm += __shfl_xor(sm, 32);
            if (l < 32) tile[x4 * 33 + ch] = mx + sm * (1.f / 16.f);
        }
        // wave-private tile: lgkmcnt ordering handled by compiler, no barrier needed
        const int cl = l & 31, oxp = l >> 5;
#pragma unroll
        for (int it = 0; it < 16; ++it) {
            const int ox = it * 2 + oxp;
            const float v = tile[ox * 33 + cl];
            p1t[((size_t)b * Nn + oy * 32 + ox) * Cn + w * 32 + cl] = v;
        }
        return;
    }

    // ---------------- convpool: 1x1 conv (bf16 MFMA) + max+avg pool -> p2t[b][n][c] -------
    const int bid2 = bid - 256;
    const int b = bid2 >> 7;
    const int r = bid2 & 127;
    const int oy = r >> 2, xq = r & 3;

    // ---- stage: 2 tasks/thread, 4 channel-strided float4 each (8x128B segments per instr)
    f32x4 ra[2][4];
    int x4v[2], rowv[2], k4v[2];
#pragma unroll
    for (int h = 0; h < 2; ++h) {
        const int i = t + h * 512;
        x4v[h] = i & 7; rowv[h] = (i >> 3) & 3; k4v[h] = i >> 5;
        const float* p = in2 + ((size_t)(b * CIN + k4v[h] * 4) * Wd + oy * 4 + rowv[h]) * Hd
                         + xq * 32 + x4v[h] * 4;
#pragma unroll
        for (int kk2 = 0; kk2 < 4; ++kk2)
            ra[h][kk2] = ldnt(p + (size_t)kk2 * Wd * Hd);
    }

    // ---- B fragments (weights) in registers
    const int n_lo = l & 15;
    const int khi = l >> 4;
    short8 bfrag[2][4];
#pragma unroll
    for (int f = 0; f < 2; ++f) {
        const int n = w * 32 + f * 16 + n_lo;
#pragma unroll
        for (int kk = 0; kk < 4; ++kk) {
            const float* wp = cw + n * CIN + kk * 32 + khi * 8;
            f32x4 va = *reinterpret_cast<const f32x4*>(wp);
            f32x4 vb = *reinterpret_cast<const f32x4*>(wp + 4);
            short8 s;
            s[0] = (short)bf16_rne(va[0]); s[1] = (short)bf16_rne(va[1]);
            s[2] = (short)bf16_rne(va[2]); s[3] = (short)bf16_rne(va[3]);
            s[4] = (short)bf16_rne(vb[0]); s[5] = (short)bf16_rne(vb[1]);
            s[6] = (short)bf16_rne(vb[2]); s[7] = (short)bf16_rne(vb[3]);
            bfrag[f][kk] = s;
        }
    }
    const float bias2_0 = 2.f * cb[w * 32 + n_lo];
    const float bias2_1 = 2.f * cb[w * 32 + 16 + n_lo];

    // ---- transpose + swizzled LDS write: A[px][k] bf16, px = cell*16 + dy*4 + dx
#pragma unroll
    for (int h = 0; h < 2; ++h) {
#pragma unroll
        for (int j = 0; j < 4; ++j) {
            const int px = x4v[h] * 16 + rowv[h] * 4 + j;
            uint2 u;
            u.x = (unsigned int)bf16_rne(ra[h][0][j]) | ((unsigned int)bf16_rne(ra[h][1][j]) << 16);
            u.y = (unsigned int)bf16_rne(ra[h][2][j]) | ((unsigned int)bf16_rne(ra[h][3][j]) << 16);
            const int off = px * 256 + ((k4v[h] * 8) ^ (fsw(px) << 4));
            *reinterpret_cast<uint2*>(smem + off) = u;
        }
    }
    __syncthreads();

    // ---- per-wave: 8 cells x 2 n-tiles; K=128 inner, pool epilogue per cell
#pragma unroll
    for (int cl = 0; cl < 8; ++cl) {
        f32x4 acc0 = {0.f, 0.f, 0.f, 0.f};
        f32x4 acc1 = {0.f, 0.f, 0.f, 0.f};
        const int px = cl * 16 + n_lo;
        const int sw = fsw(px) << 4;
#pragma unroll
        for (int kk = 0; kk < 4; ++kk) {
            short8 a = *reinterpret_cast<const short8*>(
                smem + px * 256 + ((kk * 64 + khi * 16) ^ sw));
            acc0 = __builtin_amdgcn_mfma_f32_16x16x32_bf16(a, bfrag[0][kk], acc0, 0, 0, 0);
            acc1 = __builtin_amdgcn_mfma_f32_16x16x32_bf16(a, bfrag[1][kk], acc1, 0, 0, 0);
        }
        float mx0 = fmaxf(fmaxf(acc0[0], acc0[1]), fmaxf(acc0[2], acc0[3]));
        float sm0 = (acc0[0] + acc0[1]) + (acc0[2] + acc0[3]);
        float mx1 = fmaxf(fmaxf(acc1[0], acc1[1]), fmaxf(acc1[2], acc1[3]));
        float sm1 = (acc1[0] + acc1[1]) + (acc1[2] + acc1[3]);
        mx0 = fmaxf(mx0, __shfl_xor(mx0, 16)); sm0 += __shfl_xor(sm0, 16);
        mx0 = fmaxf(mx0, __shfl_xor(mx0, 32)); sm0 += __shfl_xor(sm0, 32);
        mx1 = fmaxf(mx1, __shfl_xor(mx1, 16)); sm1 += __shfl_xor(sm1, 16);
        mx1 = fmaxf(mx1, __shfl_xor(mx1, 32)); sm1 += __shfl_xor(sm1, 32);
        if (l < 16) {
            const int cell = oy * 32 + xq * 8 + cl;
            float* dst = p2t + ((size_t)b * Nn + cell) * Cn + w * 32 + n_lo;
            dst[0]  = mx0 + sm0 * (1.f / 16.f) + bias2_0;
            dst[16] = mx1 + sm1 * (1.f / 16.f) + bias2_1;
        }
    }
}

// ---------------- Kernel 2: per-cell cross-batch attention -> att[b][c][n] ----------------
__global__ __launch_bounds__(256) void attn_kernel(const float* __restrict__ p1t,
                                                   const float* __restrict__ p2t,
                                                   float* __restrict__ att) {
    __shared__ float q[Bn][260];
    __shared__ float kk[Bn][260];
    __shared__ float wsm[Bn][8];
    const int n = blockIdx.x, t = threadIdx.x;

#pragma unroll
    for (int i = 0; i < 2; ++i) {
        const int f = t + i * 256;
        const int bb = f >> 6, cq = f & 63;
        const size_t off = ((size_t)bb * Nn + n) * Cn + cq * 4;
        *reinterpret_cast<float4*>(&q[bb][cq * 4])  = *reinterpret_cast<const float4*>(p1t + off);
        *reinterpret_cast<float4*>(&kk[bb][cq * 4]) = *reinterpret_cast<const float4*>(p2t + off);
    }
    __syncthreads();

    {
        const int chunk = t & 3, pair = t >> 2;
        const int e = pair & 7, bb = pair >> 3;
        float s = 0.f;
#pragma unroll
        for (int i = 0; i < 64; ++i)
            s = fmaf(q[bb][i * 4 + chunk], kk[e][i * 4 + chunk], s);
        s += __shfl_xor(s, 1);
        s += __shfl_xor(s, 2);
        s *= 0.17677669529663687f;            // 1/sqrt(32)
        float m = fmaxf(s, __shfl_xor(s, 4));
        m = fmaxf(m, __shfl_xor(m, 8));
        m = fmaxf(m, __shfl_xor(m, 16));
        float p = __expf(s - m);
        float d = p + __shfl_xor(p, 4);
        d += __shfl_xor(d, 8);
        d += __shfl_xor(d, 16);
        if (chunk == 0) wsm[bb][e] = p / d;
    }
    __syncthreads();

    float kv[8];
#pragma unroll
    for (int e = 0; e < 8; ++e) kv[e] = kk[e][t];
#pragma unroll
    for (int bb = 0; bb < 8; ++bb) {
        float s = 0.f;
#pragma unroll
        for (int e = 0; e < 8; ++e) s = fmaf(wsm[bb][e], kv[e], s);
        att[((size_t)bb * Cn + t) * Nn + n] = s;
    }
}

// ---------------- Kernel 3: bilinear upsample (align_corners) + sigmoid ----------------
__global__ __launch_bounds__(256) void upsample_kernel(const float* __restrict__ att,
                                                       float* __restrict__ out) {
    __shared__ float tile[ATTn * ATTn];
    int bc = blockIdx.x, t = threadIdx.x;
    reinterpret_cast<float4*>(tile)[t] =
        reinterpret_cast<const float4*>(att + (size_t)bc * Nn)[t];
    __syncthreads();

    int tx = t & 31, ty = t >> 5;
    int xi0[4], xi1[4];
    float xt[4];
#pragma unroll
    for (int j = 0; j < 4; ++j) {
        int x = tx * 4 + j;
        float pos = (float)x * (31.f / 127.f);
        int i0 = (int)pos;
        xi0[j] = i0;
        xi1[j] = min(i0 + 1, 31);
        xt[j] = pos - (float)i0;
    }

    for (int r = 0; r < 16; ++r) {
        int y = ty + r * 8;
        float posy = (float)y * (31.f / 127.f);
        int y0 = (int)posy;
        int y1 = min(y0 + 1, 31);
        float ft = posy - (float)y0;
        float o_[4];
#pragma unroll
        for (int j = 0; j < 4; ++j) {
            float v00 = tile[y0 * 32 + xi0[j]];
            float v01 = tile[y0 * 32 + xi1[j]];
            float v10 = tile[y1 * 32 + xi0[j]];
            float v11 = tile[y1 * 32 + xi1[j]];
            float top = v00 * (1.f - ft) + v10 * ft;
            float bot = v01 * (1.f - ft) + v11 * ft;
            float val = top * (1.f - xt[j]) + bot * xt[j];
            o_[j] = 1.f / (1.f + __expf(-val));
        }
        *reinterpret_cast<float4*>(out + ((size_t)bc * Wd + y) * Hd + tx * 4) =
            make_float4(o_[0], o_[1], o_[2], o_[3]);
    }
}

}  // namespace

extern "C" void kernel_launch(void* const* d_in, const int* in_sizes, int n_in,
                              void* d_out, int out_size, void* d_ws, size_t ws_size,
                              hipStream_t stream) {
    const float* input1 = (const float*)d_in[0];
    const float* input2 = (const float*)d_in[1];
    const float* conv_w = (const float*)d_in[2];
    const float* conv_b = (const float*)d_in[3];
    float* out = (float*)d_out;

    float* p1t = (float*)d_ws;                        // [B][N][C] 8 MB
    float* p2t = p1t + (size_t)Bn * Cn * Nn;          // [B][N][C] 8 MB
    float* att = p2t + (size_t)Bn * Cn * Nn;          // [B][C][N] 8 MB

    front_kernel<<<dim3(1280), dim3(512), 0, stream>>>(input1, input2, conv_w, conv_b, p1t, p2t);
    attn_kernel<<<dim3(Nn), dim3(256), 0, stream>>>(p1t, p2t, att);
    upsample_kernel<<<dim3(Bn * Cn), dim3(256), 0, stream>>>(att, out);
}

// Round 12
// 100.829 us; speedup vs baseline: 1.4542x; 1.0392x over previous
//
#include <hip/hip_runtime.h>
#include <math.h>

namespace {

constexpr int Bn = 8, Cn = 256, CIN = 128, Wd = 128, Hd = 128, ATTn = 32, Nn = ATTn * ATTn;

typedef __attribute__((ext_vector_type(8))) short short8;
typedef __attribute__((ext_vector_type(4))) float f32x4;

__device__ inline unsigned short bf16_rne(float f) {
    unsigned int u = __float_as_uint(f);
    unsigned int r = (u + 0x7FFFu + ((u >> 16) & 1u)) >> 16;
    return (unsigned short)r;
}

__device__ inline int fsw(int px) { return (px ^ (px >> 3)) & 7; }

__device__ inline f32x4 ldnt(const float* p) {
    return __builtin_nontemporal_load(reinterpret_cast<const f32x4*>(p));
}

// ============ Fused front kernel ============
// blocks [0,2048):    pool1 v8 — block (b, oy8, cg16): 8 indep nt loads/thread, 1 barrier.
// blocks [2048,3072): convpool — block (b,oy,xq); one-shot stage + 1 barrier + MFMA (r11).
__global__ __launch_bounds__(512, 4) void front_kernel(const float* __restrict__ in1,
                                                       const float* __restrict__ in2,
                                                       const float* __restrict__ cw,
                                                       const float* __restrict__ cb,
                                                       float* __restrict__ p1t,
                                                       float* __restrict__ p2t) {
    __shared__ __align__(16) unsigned char smem[33792];

    const int t = threadIdx.x;
    const int bid = blockIdx.x;
    const int w = t >> 6;                 // wave 0..7
    const int l = t & 63;                 // lane

    if (bid < 2048) {
        // ---------------- pool1 v8: block (b, oy8(16 rows? no: 8 rows), cg:16 ch) ---------
        // b = bid>>8, oy8 = (bid>>4)&15 (rows oy8*8..+7 -> windows oy8*2, oy8*2+1),
        // cg = bid&15 (channels cg*16..+15).
        const int b = bid >> 8, oy8 = (bid >> 4) & 15, cg = bid & 15;
        const int ox = t & 31, c16 = t >> 5;      // c16 0..15
        float* tile = reinterpret_cast<float*>(smem);   // [2][32][17]

        const float* src = in1 + (((size_t)(b * Cn + cg * 16 + c16) * Wd) + oy8 * 8) * Hd
                           + ox * 4;
        f32x4 r[8];
#pragma unroll
        for (int j = 0; j < 8; ++j) r[j] = ldnt(src + (size_t)j * Hd);

        float mx0 = -INFINITY, sm0 = 0.f, mx1 = -INFINITY, sm1 = 0.f;
#pragma unroll
        for (int j = 0; j < 4; ++j) {
            mx0 = fmaxf(mx0, fmaxf(fmaxf(r[j][0], r[j][1]), fmaxf(r[j][2], r[j][3])));
            sm0 += (r[j][0] + r[j][1]) + (r[j][2] + r[j][3]);
        }
#pragma unroll
        for (int j = 4; j < 8; ++j) {
            mx1 = fmaxf(mx1, fmaxf(fmaxf(r[j][0], r[j][1]), fmaxf(r[j][2], r[j][3])));
            sm1 += (r[j][0] + r[j][1]) + (r[j][2] + r[j][3]);
        }
        tile[0 * 544 + ox * 17 + c16] = mx0 + sm0 * (1.f / 16.f);
        tile[1 * 544 + ox * 17 + c16] = mx1 + sm1 * (1.f / 16.f);
        __syncthreads();

#pragma unroll
        for (int j = 0; j < 2; ++j) {
            const int idx = t + j * 512;
            const int wnd = idx >> 9, rr = idx & 511, ox2 = rr >> 4, cc = rr & 15;
            p1t[((size_t)b * Nn + (oy8 * 2 + wnd) * 32 + ox2) * Cn + cg * 16 + cc] =
                tile[wnd * 544 + ox2 * 17 + cc];
        }
        return;
    }

    // ---------------- convpool: 1x1 conv (bf16 MFMA) + max+avg pool -> p2t[b][n][c] -------
    const int bid2 = bid - 2048;
    const int b = bid2 >> 7;
    const int r = bid2 & 127;
    const int oy = r >> 2, xq = r & 3;

    // ---- stage: 2 tasks/thread, 4 channel-strided float4 each
    f32x4 ra[2][4];
    int x4v[2], rowv[2], k4v[2];
#pragma unroll
    for (int h = 0; h < 2; ++h) {
        const int i = t + h * 512;
        x4v[h] = i & 7; rowv[h] = (i >> 3) & 3; k4v[h] = i >> 5;
        const float* p = in2 + ((size_t)(b * CIN + k4v[h] * 4) * Wd + oy * 4 + rowv[h]) * Hd
                         + xq * 32 + x4v[h] * 4;
#pragma unroll
        for (int kk2 = 0; kk2 < 4; ++kk2)
            ra[h][kk2] = ldnt(p + (size_t)kk2 * Wd * Hd);
    }

    // ---- B fragments (weights) in registers
    const int n_lo = l & 15;
    const int khi = l >> 4;
    short8 bfrag[2][4];
#pragma unroll
    for (int f = 0; f < 2; ++f) {
        const int n = w * 32 + f * 16 + n_lo;
#pragma unroll
        for (int kk = 0; kk < 4; ++kk) {
            const float* wp = cw + n * CIN + kk * 32 + khi * 8;
            f32x4 va = *reinterpret_cast<const f32x4*>(wp);
            f32x4 vb = *reinterpret_cast<const f32x4*>(wp + 4);
            short8 s;
            s[0] = (short)bf16_rne(va[0]); s[1] = (short)bf16_rne(va[1]);
            s[2] = (short)bf16_rne(va[2]); s[3] = (short)bf16_rne(va[3]);
            s[4] = (short)bf16_rne(vb[0]); s[5] = (short)bf16_rne(vb[1]);
            s[6] = (short)bf16_rne(vb[2]); s[7] = (short)bf16_rne(vb[3]);
            bfrag[f][kk] = s;
        }
    }
    const float bias2_0 = 2.f * cb[w * 32 + n_lo];
    const float bias2_1 = 2.f * cb[w * 32 + 16 + n_lo];

    // ---- transpose + swizzled LDS write: A[px][k] bf16
#pragma unroll
    for (int h = 0; h < 2; ++h) {
#pragma unroll
        for (int j = 0; j < 4; ++j) {
            const int px = x4v[h] * 16 + rowv[h] * 4 + j;
            uint2 u;
            u.x = (unsigned int)bf16_rne(ra[h][0][j]) | ((unsigned int)bf16_rne(ra[h][1][j]) << 16);
            u.y = (unsigned int)bf16_rne(ra[h][2][j]) | ((unsigned int)bf16_rne(ra[h][3][j]) << 16);
            const int off = px * 256 + ((k4v[h] * 8) ^ (fsw(px) << 4));
            *reinterpret_cast<uint2*>(smem + off) = u;
        }
    }
    __syncthreads();

    // ---- per-wave: 8 cells x 2 n-tiles; K=128 inner, pool epilogue per cell
#pragma unroll
    for (int cl = 0; cl < 8; ++cl) {
        f32x4 acc0 = {0.f, 0.f, 0.f, 0.f};
        f32x4 acc1 = {0.f, 0.f, 0.f, 0.f};
        const int px = cl * 16 + n_lo;
        const int sw = fsw(px) << 4;
#pragma unroll
        for (int kk = 0; kk < 4; ++kk) {
            short8 a = *reinterpret_cast<const short8*>(
                smem + px * 256 + ((kk * 64 + khi * 16) ^ sw));
            acc0 = __builtin_amdgcn_mfma_f32_16x16x32_bf16(a, bfrag[0][kk], acc0, 0, 0, 0);
            acc1 = __builtin_amdgcn_mfma_f32_16x16x32_bf16(a, bfrag[1][kk], acc1, 0, 0, 0);
        }
        float mx0 = fmaxf(fmaxf(acc0[0], acc0[1]), fmaxf(acc0[2], acc0[3]));
        float sm0 = (acc0[0] + acc0[1]) + (acc0[2] + acc0[3]);
        float mx1 = fmaxf(fmaxf(acc1[0], acc1[1]), fmaxf(acc1[2], acc1[3]));
        float sm1 = (acc1[0] + acc1[1]) + (acc1[2] + acc1[3]);
        mx0 = fmaxf(mx0, __shfl_xor(mx0, 16)); sm0 += __shfl_xor(sm0, 16);
        mx0 = fmaxf(mx0, __shfl_xor(mx0, 32)); sm0 += __shfl_xor(sm0, 32);
        mx1 = fmaxf(mx1, __shfl_xor(mx1, 16)); sm1 += __shfl_xor(sm1, 16);
        mx1 = fmaxf(mx1, __shfl_xor(mx1, 32)); sm1 += __shfl_xor(sm1, 32);
        if (l < 16) {
            const int cell = oy * 32 + xq * 8 + cl;
            float* dst = p2t + ((size_t)b * Nn + cell) * Cn + w * 32 + n_lo;
            dst[0]  = mx0 + sm0 * (1.f / 16.f) + bias2_0;
            dst[16] = mx1 + sm1 * (1.f / 16.f) + bias2_1;
        }
    }
}

// ---------------- Kernel 2: per-cell cross-batch attention -> att[b][c][n] ----------------
__global__ __launch_bounds__(256) void attn_kernel(const float* __restrict__ p1t,
                                                   const float* __restrict__ p2t,
                                                   float* __restrict__ att) {
    __shared__ float q[Bn][260];
    __shared__ float kk[Bn][260];
    __shared__ float wsm[Bn][8];
    const int n = blockIdx.x, t = threadIdx.x;

#pragma unroll
    for (int i = 0; i < 2; ++i) {
        const int f = t + i * 256;
        const int bb = f >> 6, cq = f & 63;
        const size_t off = ((size_t)bb * Nn + n) * Cn + cq * 4;
        *reinterpret_cast<float4*>(&q[bb][cq * 4])  = *reinterpret_cast<const float4*>(p1t + off);
        *reinterpret_cast<float4*>(&kk[bb][cq * 4]) = *reinterpret_cast<const float4*>(p2t + off);
    }
    __syncthreads();

    {
        const int chunk = t & 3, pair = t >> 2;
        const int e = pair & 7, bb = pair >> 3;
        float s = 0.f;
#pragma unroll
        for (int i = 0; i < 64; ++i)
            s = fmaf(q[bb][i * 4 + chunk], kk[e][i * 4 + chunk], s);
        s += __shfl_xor(s, 1);
        s += __shfl_xor(s, 2);
        s *= 0.17677669529663687f;            // 1/sqrt(32)
        float m = fmaxf(s, __shfl_xor(s, 4));
        m = fmaxf(m, __shfl_xor(m, 8));
        m = fmaxf(m, __shfl_xor(m, 16));
        float p = __expf(s - m);
        float d = p + __shfl_xor(p, 4);
        d += __shfl_xor(d, 8);
        d += __shfl_xor(d, 16);
        if (chunk == 0) wsm[bb][e] = p / d;
    }
    __syncthreads();

    float kv[8];
#pragma unroll
    for (int e = 0; e < 8; ++e) kv[e] = kk[e][t];
#pragma unroll
    for (int bb = 0; bb < 8; ++bb) {
        float s = 0.f;
#pragma unroll
        for (int e = 0; e < 8; ++e) s = fmaf(wsm[bb][e], kv[e], s);
        att[((size_t)bb * Cn + t) * Nn + n] = s;
    }
}

// ---------------- Kernel 3: bilinear upsample (align_corners) + sigmoid ----------------
__global__ __launch_bounds__(256) void upsample_kernel(const float* __restrict__ att,
                                                       float* __restrict__ out) {
    __shared__ float tile[ATTn * ATTn];
    int bc = blockIdx.x, t = threadIdx.x;
    reinterpret_cast<float4*>(tile)[t] =
        reinterpret_cast<const float4*>(att + (size_t)bc * Nn)[t];
    __syncthreads();

    int tx = t & 31, ty = t >> 5;
    int xi0[4], xi1[4];
    float xt[4];
#pragma unroll
    for (int j = 0; j < 4; ++j) {
        int x = tx * 4 + j;
        float pos = (float)x * (31.f / 127.f);
        int i0 = (int)pos;
        xi0[j] = i0;
        xi1[j] = min(i0 + 1, 31);
        xt[j] = pos - (float)i0;
    }

    for (int r = 0; r < 16; ++r) {
        int y = ty + r * 8;
        float posy = (float)y * (31.f / 127.f);
        int y0 = (int)posy;
        int y1 = min(y0 + 1, 31);
        float ft = posy - (float)y0;
        float o_[4];
#pragma unroll
        for (int j = 0; j < 4; ++j) {
            float v00 = tile[y0 * 32 + xi0[j]];
            float v01 = tile[y0 * 32 + xi1[j]];
            float v10 = tile[y1 * 32 + xi0[j]];
            float v11 = tile[y1 * 32 + xi1[j]];
            float top = v00 * (1.f - ft) + v10 * ft;
            float bot = v01 * (1.f - ft) + v11 * ft;
            float val = top * (1.f - xt[j]) + bot * xt[j];
            o_[j] = 1.f / (1.f + __expf(-val));
        }
        *reinterpret_cast<float4*>(out + ((size_t)bc * Wd + y) * Hd + tx * 4) =
            make_float4(o_[0], o_[1], o_[2], o_[3]);
    }
}

}  // namespace

extern "C" void kernel_launch(void* const* d_in, const int* in_sizes, int n_in,
                              void* d_out, int out_size, void* d_ws, size_t ws_size,
                              hipStream_t stream) {
    const float* input1 = (const float*)d_in[0];
    const float* input2 = (const float*)d_in[1];
    const float* conv_w = (const float*)d_in[2];
    const float* conv_b = (const float*)d_in[3];
    float* out = (float*)d_out;

    float* p1t = (float*)d_ws;                        // [B][N][C] 8 MB
    float* p2t = p1t + (size_t)Bn * Cn * Nn;          // [B][N][C] 8 MB
    float* att = p2t + (size_t)Bn * Cn * Nn;          // [B][C][N] 8 MB

    front_kernel<<<dim3(3072), dim3(512), 0, stream>>>(input1, input2, conv_w, conv_b, p1t, p2t);
    attn_kernel<<<dim3(Nn), dim3(256), 0, stream>>>(p1t, p2t, att);
    upsample_kernel<<<dim3(Bn * Cn), dim3(256), 0, stream>>>(att, out);
}